// Round 1
// baseline (411.386 us; speedup 1.0000x reference)
//
#include <hip/hip_runtime.h>

// Swin window attention, fully fused: roll -> QKV (bf16 MFMA) -> windowed
// attention (bf16 MFMA, fp32 softmax) -> out-proj (bf16 MFMA) -> roll back.
// One block per (batch, window): 16*256 = 4096 blocks, 256 threads (4 waves).
// Wave w owns head w during attention phases.
//
// MFMA 16x16x32 bf16 fragment layouts (HW-verified per guide m89/m91/m120):
//   A[m][k]: m = lane&15, k = (lane>>4)*8 + j   (8 contiguous bf16 = 16B)
//   B[k][n]: n = lane&15, k = (lane>>4)*8 + j
//   D[m][n]: n = lane&15, m = (lane>>4)*4 + reg
// So "row-major [row][k-contig]" LDS tiles serve A directly, and [n][k-contig]
// (i.e. transposed weights) serve B directly.

typedef __bf16 bf16x8 __attribute__((ext_vector_type(8)));
typedef short  s16x8  __attribute__((ext_vector_type(8)));
typedef float  f32x4  __attribute__((ext_vector_type(4)));

static __device__ __forceinline__ float bf2f(unsigned short u) {
  unsigned x = ((unsigned)u) << 16;
  return __builtin_bit_cast(float, x);
}
static __device__ __forceinline__ unsigned short f2bf(float f) {
  unsigned x = __builtin_bit_cast(unsigned, f);
  x += 0x7FFFu + ((x >> 16) & 1u);   // round-to-nearest-even
  return (unsigned short)(x >> 16);
}
static __device__ __forceinline__ f32x4 mfma16(s16x8 a, s16x8 b, f32x4 c) {
  return __builtin_amdgcn_mfma_f32_16x16x32_bf16(
      __builtin_bit_cast(bf16x8, a), __builtin_bit_cast(bf16x8, b), c, 0, 0, 0);
}

// ---------------- prep: transpose + bf16-cast weights into workspace --------
// wqkvT[n][k] = bf16(w_qkv[k][n])  (384 x 128)
// woutT[n][k] = bf16(w_out[k][n])  (128 x 128)
__global__ void prep_weights(const float* __restrict__ wqkv,
                             const float* __restrict__ wout,
                             unsigned short* __restrict__ wqkvT,
                             unsigned short* __restrict__ woutT) {
  int idx = blockIdx.x * blockDim.x + threadIdx.x;
  const int total1 = 384 * 128;
  if (idx < total1) {
    int n = idx >> 7, k = idx & 127;
    wqkvT[idx] = f2bf(wqkv[k * 384 + n]);
  } else {
    int i2 = idx - total1;              // < 128*128 by grid construction
    int n = i2 >> 7, k = i2 & 127;
    woutT[i2] = f2bf(wout[k * 128 + n]);
  }
}

// ---------------- fused main kernel -----------------------------------------
// LDS regions (bytes):
//   q    [64][136] bf16   17408   @ 0
//   k    [64][136] bf16   17408   @ 17408
//   v    [128][72] bf16   18432   @ 34816   (v transposed: [ch][tok])
//   S    [4][64][72] bf16 36864   @ 53248   (union: xs [64][136] bf16 staging)
//   bias [64][65] f32     16640   @ 90112   (union: out_attn [64][136] bf16)
//   rsum [4][64] f32       1024   @ 107520
//   total 108544
#define OFF_Q   0
#define OFF_K   17408
#define OFF_V   34816
#define OFF_S   53248
#define OFF_BO  90112
#define OFF_RS  107520
#define SMEM_SZ 108544

__global__ __launch_bounds__(256, 1)
void swin_fused(const float* __restrict__ x,
                const unsigned short* __restrict__ wqkvT,
                const unsigned short* __restrict__ woutT,
                const float* __restrict__ b_out,
                const float* __restrict__ pe,     // [15][15]
                const float* __restrict__ ulm,    // [64][64]
                const float* __restrict__ lrm,    // [64][64]
                float* __restrict__ out) {
  __shared__ __align__(16) unsigned char smem[SMEM_SZ];
  unsigned short* q_s  = (unsigned short*)(smem + OFF_Q);
  unsigned short* k_s  = (unsigned short*)(smem + OFF_K);
  unsigned short* v_s  = (unsigned short*)(smem + OFF_V);
  unsigned short* S_s  = (unsigned short*)(smem + OFF_S);
  unsigned short* xs_s = S_s;                       // union
  float*          bias_s = (float*)(smem + OFF_BO);
  unsigned short* oa_s   = (unsigned short*)(smem + OFF_BO); // union
  float*          rsum_s = (float*)(smem + OFF_RS);

  const int tid  = threadIdx.x;
  const int lane = tid & 63;
  const int wave = tid >> 6;
  const int ln15 = lane & 15;
  const int quad = lane >> 4;
  const int m_sub = quad << 2;

  const int bid = blockIdx.x;
  const int b   = bid >> 8;
  const int w   = bid & 255;
  const int wh  = w >> 4, ww = w & 15;

  // ---- phase 0: stage rolled x window to LDS (bf16) + build bias ----
  {
    const int row0 = wh * 8, col0 = ww * 8;
#pragma unroll
    for (int it = 0; it < 8; ++it) {
      int t = tid + it * 256;              // 2048 float4 chunks total
      int tok = t >> 5, c4 = t & 31;
      int ti = tok >> 3, tj = tok & 7;
      int gi = (row0 + ti + 4) & 127;
      int gj = (col0 + tj + 4) & 127;
      float4 v4 = *(const float4*)(x + (((b * 128 + gi) * 128 + gj) * 128 + c4 * 4));
      ushort4 pk;
      pk.x = f2bf(v4.x); pk.y = f2bf(v4.y); pk.z = f2bf(v4.z); pk.w = f2bf(v4.w);
      *(ushort4*)(xs_s + tok * 136 + c4 * 4) = pk;
    }
    const bool has_ul = (wh == 15), has_lr = (ww == 15);
#pragma unroll
    for (int it = 0; it < 16; ++it) {
      int t = tid + it * 256;              // 4096 bias entries
      int i = t >> 6, j = t & 63;
      int r0 = (j >> 3) - (i >> 3) + 7;    // rel = idx[key] - idx[query]
      int r1 = (j & 7) - (i & 7) + 7;
      float bsum = pe[r0 * 15 + r1];
      if (has_ul) bsum += ulm[t];
      if (has_lr) bsum += lrm[t];
      bias_s[i * 65 + j] = bsum;
    }
  }
  __syncthreads();

  // ---- phase 1: QKV GEMM (M=64 tokens, K=128, N=384; wave n-slice = 96) ----
  {
    s16x8 a[4][4];
#pragma unroll
    for (int mt = 0; mt < 4; ++mt)
#pragma unroll
      for (int ks = 0; ks < 4; ++ks)
        a[mt][ks] = *(const s16x8*)(xs_s + (mt * 16 + ln15) * 136 + ks * 32 + quad * 8);

#pragma unroll
    for (int t6 = 0; t6 < 6; ++t6) {
      int n0 = wave * 96 + t6 * 16;
      int n  = n0 + ln15;
      s16x8 bf[4];
      const unsigned short* wp = wqkvT + n * 128 + quad * 8;
#pragma unroll
      for (int ks = 0; ks < 4; ++ks) bf[ks] = *(const s16x8*)(wp + ks * 32);
#pragma unroll
      for (int mt = 0; mt < 4; ++mt) {
        f32x4 acc = {0.f, 0.f, 0.f, 0.f};
#pragma unroll
        for (int ks = 0; ks < 4; ++ks) acc = mfma16(a[mt][ks], bf[ks], acc);
        int tok0 = mt * 16 + m_sub;
        if (n0 < 128) {               // q
#pragma unroll
          for (int r = 0; r < 4; ++r) q_s[(tok0 + r) * 136 + n] = f2bf(acc[r]);
        } else if (n0 < 256) {        // k
          int nn = n - 128;
#pragma unroll
          for (int r = 0; r < 4; ++r) k_s[(tok0 + r) * 136 + nn] = f2bf(acc[r]);
        } else {                      // v (transposed [ch][tok], tok0 % 4 == 0)
          int nn = n - 256;
          ushort4 pk;
          pk.x = f2bf(acc[0]); pk.y = f2bf(acc[1]);
          pk.z = f2bf(acc[2]); pk.w = f2bf(acc[3]);
          *(ushort4*)(v_s + nn * 72 + tok0) = pk;
        }
      }
    }
  }
  __syncthreads();

  // ---- phase 2: QK^T * scale + bias -> S (bf16); wave = head ----
  const int h = wave;
  {
    unsigned short* Sh = S_s + h * 64 * 72;
    s16x8 qf[4], kf[4];
#pragma unroll
    for (int mt = 0; mt < 4; ++mt)
      qf[mt] = *(const s16x8*)(q_s + (mt * 16 + ln15) * 136 + h * 32 + quad * 8);
#pragma unroll
    for (int nt = 0; nt < 4; ++nt)
      kf[nt] = *(const s16x8*)(k_s + (nt * 16 + ln15) * 136 + h * 32 + quad * 8);
    const float scale = 0.17677669529663687f;   // 32^-0.5
#pragma unroll
    for (int mt = 0; mt < 4; ++mt) {
#pragma unroll
      for (int nt = 0; nt < 4; ++nt) {
        f32x4 acc = {0.f, 0.f, 0.f, 0.f};
        acc = mfma16(qf[mt], kf[nt], acc);
        int nn = nt * 16 + ln15;
        int tok0 = mt * 16 + m_sub;
#pragma unroll
        for (int r = 0; r < 4; ++r) {
          float sv = acc[r] * scale + bias_s[(tok0 + r) * 65 + nn];
          Sh[(tok0 + r) * 72 + nn] = f2bf(sv);
        }
      }
    }
  }
  __syncthreads();

  // ---- phase 3: softmax rows (lane = row), exp back into S, recip sums ----
  {
    unsigned short* row = S_s + h * 64 * 72 + lane * 72;
    float vals[64];
    float mx = -1e30f;
#pragma unroll
    for (int c = 0; c < 8; ++c) {
      s16x8 s8 = *(const s16x8*)(row + c * 8);
#pragma unroll
      for (int j = 0; j < 8; ++j) {
        float f = bf2f((unsigned short)s8[j]);
        vals[c * 8 + j] = f;
        mx = fmaxf(mx, f);
      }
    }
    float sum = 0.f;
#pragma unroll
    for (int c = 0; c < 8; ++c) {
      s16x8 st;
#pragma unroll
      for (int j = 0; j < 8; ++j) {
        float e = __expf(vals[c * 8 + j] - mx);
        sum += e;
        st[j] = (short)f2bf(e);
      }
      *(s16x8*)(row + c * 8) = st;
    }
    rsum_s[h * 64 + lane] = 1.0f / sum;   // sum >= 1 (max elem contributes 1)
  }
  __syncthreads();

  // ---- phase 4: PV (M=64, K=64 keys, N=32 dims), normalize, -> out_attn ----
  {
    unsigned short* Sh = S_s + h * 64 * 72;
    s16x8 pf[4][2], vf[2][2];
#pragma unroll
    for (int mt = 0; mt < 4; ++mt)
#pragma unroll
      for (int ks = 0; ks < 2; ++ks)
        pf[mt][ks] = *(const s16x8*)(Sh + (mt * 16 + ln15) * 72 + ks * 32 + quad * 8);
#pragma unroll
    for (int nt = 0; nt < 2; ++nt)
#pragma unroll
      for (int ks = 0; ks < 2; ++ks)
        vf[nt][ks] = *(const s16x8*)(v_s + (h * 32 + nt * 16 + ln15) * 72 + ks * 32 + quad * 8);
#pragma unroll
    for (int mt = 0; mt < 4; ++mt) {
      int tok0 = mt * 16 + m_sub;
      float rc[4];
#pragma unroll
      for (int r = 0; r < 4; ++r) rc[r] = rsum_s[h * 64 + tok0 + r];
#pragma unroll
      for (int nt = 0; nt < 2; ++nt) {
        f32x4 acc = {0.f, 0.f, 0.f, 0.f};
#pragma unroll
        for (int ks = 0; ks < 2; ++ks) acc = mfma16(pf[mt][ks], vf[nt][ks], acc);
        int n = h * 32 + nt * 16 + ln15;
#pragma unroll
        for (int r = 0; r < 4; ++r)
          oa_s[(tok0 + r) * 136 + n] = f2bf(acc[r] * rc[r]);
      }
    }
  }
  __syncthreads();

  // ---- phase 5: out projection (M=64, K=128, N=128) + bias + roll-back ----
  {
    s16x8 af[4][4];
#pragma unroll
    for (int mt = 0; mt < 4; ++mt)
#pragma unroll
      for (int ks = 0; ks < 4; ++ks)
        af[mt][ks] = *(const s16x8*)(oa_s + (mt * 16 + ln15) * 136 + ks * 32 + quad * 8);
#pragma unroll
    for (int t2 = 0; t2 < 2; ++t2) {
      int n = wave * 32 + t2 * 16 + ln15;
      s16x8 bf[4];
      const unsigned short* wp = woutT + n * 128 + quad * 8;
#pragma unroll
      for (int ks = 0; ks < 4; ++ks) bf[ks] = *(const s16x8*)(wp + ks * 32);
      float bo = b_out[n];
#pragma unroll
      for (int mt = 0; mt < 4; ++mt) {
        f32x4 acc = {0.f, 0.f, 0.f, 0.f};
#pragma unroll
        for (int ks = 0; ks < 4; ++ks) acc = mfma16(af[mt][ks], bf[ks], acc);
        int tok0 = mt * 16 + m_sub;
#pragma unroll
        for (int r = 0; r < 4; ++r) {
          int tok = tok0 + r;
          int ti = tok >> 3, tj = tok & 7;
          int gi = (wh * 8 + ti + 4) & 127;
          int gj = (ww * 8 + tj + 4) & 127;
          out[((b * 128 + gi) * 128 + gj) * 128 + n] = acc[r] + bo;
        }
      }
    }
  }
}

extern "C" void kernel_launch(void* const* d_in, const int* in_sizes, int n_in,
                              void* d_out, int out_size, void* d_ws, size_t ws_size,
                              hipStream_t stream) {
  const float* x    = (const float*)d_in[0];
  const float* wqkv = (const float*)d_in[1];
  const float* wout = (const float*)d_in[2];
  const float* bout = (const float*)d_in[3];
  const float* pe   = (const float*)d_in[4];
  const float* ulm  = (const float*)d_in[5];
  const float* lrm  = (const float*)d_in[6];

  unsigned short* wqkvT = (unsigned short*)d_ws;           // 384*128 bf16
  unsigned short* woutT = wqkvT + 384 * 128;               // 128*128 bf16

  prep_weights<<<(384 * 128 + 128 * 128) / 256, 256, 0, stream>>>(wqkv, wout, wqkvT, woutT);
  swin_fused<<<16 * 256, 256, 0, stream>>>(x, wqkvT, woutT, bout, pe, ulm, lrm,
                                           (float*)d_out);
}

// Round 2
// 350.455 us; speedup vs baseline: 1.1739x; 1.1739x over previous
//
#include <hip/hip_runtime.h>

// Swin window attention, fully fused: roll -> QKV (bf16 MFMA) -> windowed
// attention (bf16 MFMA, fp32 softmax) -> out-proj (bf16 MFMA) -> roll back.
// R1 -> R2 change: 256 -> 1024 threads per block (16 waves per window).
// LDS is 108.5 KB -> 1 block/CU either way; 16 waves/CU instead of 4 gives
// 4x the latency hiding (R1 counters: Occupancy 10.3%, MfmaUtil 6.7%,
// VALUBusy 22.8%, HBM 9.8% -- pure latency-bound).
//
// MFMA 16x16x32 bf16 fragment layouts (HW-verified per guide m89/m91/m120):
//   A[m][k]: m = lane&15, k = (lane>>4)*8 + j   (8 contiguous bf16 = 16B)
//   B[k][n]: n = lane&15, k = (lane>>4)*8 + j
//   D[m][n]: n = lane&15, m = (lane>>4)*4 + reg

typedef __bf16 bf16x8 __attribute__((ext_vector_type(8)));
typedef short  s16x8  __attribute__((ext_vector_type(8)));
typedef float  f32x4  __attribute__((ext_vector_type(4)));

static __device__ __forceinline__ float bf2f(unsigned short u) {
  unsigned x = ((unsigned)u) << 16;
  return __builtin_bit_cast(float, x);
}
static __device__ __forceinline__ unsigned short f2bf(float f) {
  unsigned x = __builtin_bit_cast(unsigned, f);
  x += 0x7FFFu + ((x >> 16) & 1u);   // round-to-nearest-even
  return (unsigned short)(x >> 16);
}
static __device__ __forceinline__ f32x4 mfma16(s16x8 a, s16x8 b, f32x4 c) {
  return __builtin_amdgcn_mfma_f32_16x16x32_bf16(
      __builtin_bit_cast(bf16x8, a), __builtin_bit_cast(bf16x8, b), c, 0, 0, 0);
}

// ---------------- prep: transpose + bf16-cast weights into workspace --------
__global__ void prep_weights(const float* __restrict__ wqkv,
                             const float* __restrict__ wout,
                             unsigned short* __restrict__ wqkvT,
                             unsigned short* __restrict__ woutT) {
  int idx = blockIdx.x * blockDim.x + threadIdx.x;
  const int total1 = 384 * 128;
  if (idx < total1) {
    int n = idx >> 7, k = idx & 127;
    wqkvT[idx] = f2bf(wqkv[k * 384 + n]);
  } else {
    int i2 = idx - total1;
    int n = i2 >> 7, k = i2 & 127;
    woutT[i2] = f2bf(wout[k * 128 + n]);
  }
}

// ---------------- fused main kernel -----------------------------------------
// LDS regions (bytes):
//   q    [64][136] bf16   17408   @ 0
//   k    [64][136] bf16   17408   @ 17408
//   v    [128][72] bf16   18432   @ 34816   (v transposed: [ch][tok])
//   S    [4][64][72] bf16 36864   @ 53248   (union: xs [64][136] bf16 staging)
//   bias [64][65] f32     16640   @ 90112   (union: out_attn [64][136] bf16)
//   rsum [4][64] f32       1024   @ 107520
#define OFF_Q   0
#define OFF_K   17408
#define OFF_V   34816
#define OFF_S   53248
#define OFF_BO  90112
#define OFF_RS  107520
#define SMEM_SZ 108544

__global__ __launch_bounds__(1024, 4)
void swin_fused(const float* __restrict__ x,
                const unsigned short* __restrict__ wqkvT,
                const unsigned short* __restrict__ woutT,
                const float* __restrict__ b_out,
                const float* __restrict__ pe,     // [15][15]
                const float* __restrict__ ulm,    // [64][64]
                const float* __restrict__ lrm,    // [64][64]
                float* __restrict__ out) {
  __shared__ __align__(16) unsigned char smem[SMEM_SZ];
  unsigned short* q_s  = (unsigned short*)(smem + OFF_Q);
  unsigned short* k_s  = (unsigned short*)(smem + OFF_K);
  unsigned short* v_s  = (unsigned short*)(smem + OFF_V);
  unsigned short* S_s  = (unsigned short*)(smem + OFF_S);
  unsigned short* xs_s = S_s;                       // union
  float*          bias_s = (float*)(smem + OFF_BO);
  unsigned short* oa_s   = (unsigned short*)(smem + OFF_BO); // union
  float*          rsum_s = (float*)(smem + OFF_RS);

  const int tid  = threadIdx.x;
  const int lane = tid & 63;
  const int wave = tid >> 6;       // 0..15
  const int ln15 = lane & 15;
  const int quad = lane >> 4;
  const int m_sub = quad << 2;

  const int bid = blockIdx.x;
  const int b   = bid >> 8;
  const int w   = bid & 255;
  const int wh  = w >> 4, ww = w & 15;

  // ---- phase 0: stage rolled x window to LDS (bf16) + build bias ----
  {
    const int row0 = wh * 8, col0 = ww * 8;
#pragma unroll
    for (int it = 0; it < 2; ++it) {
      int t = tid + it * 1024;             // 2048 float4 chunks total
      int tok = t >> 5, c4 = t & 31;
      int ti = tok >> 3, tj = tok & 7;
      int gi = (row0 + ti + 4) & 127;
      int gj = (col0 + tj + 4) & 127;
      float4 v4 = *(const float4*)(x + (((b * 128 + gi) * 128 + gj) * 128 + c4 * 4));
      ushort4 pk;
      pk.x = f2bf(v4.x); pk.y = f2bf(v4.y); pk.z = f2bf(v4.z); pk.w = f2bf(v4.w);
      *(ushort4*)(xs_s + tok * 136 + c4 * 4) = pk;
    }
    const bool has_ul = (wh == 15), has_lr = (ww == 15);
#pragma unroll
    for (int it = 0; it < 4; ++it) {
      int t = tid + it * 1024;             // 4096 bias entries
      int i = t >> 6, j = t & 63;
      int r0 = (j >> 3) - (i >> 3) + 7;
      int r1 = (j & 7) - (i & 7) + 7;
      float bsum = pe[r0 * 15 + r1];
      if (has_ul) bsum += ulm[t];
      if (has_lr) bsum += lrm[t];
      bias_s[i * 65 + j] = bsum;
    }
  }
  __syncthreads();

  // ---- phase 1: QKV GEMM (M=64, K=128, N=384 = 24 n-tiles over 16 waves) --
  {
    for (int nt = wave; nt < 24; nt += 16) {   // wave-uniform trip count
      int n0 = nt * 16;
      int n  = n0 + ln15;
      s16x8 bfr[4];
      const unsigned short* wp = wqkvT + n * 128 + quad * 8;
#pragma unroll
      for (int ks = 0; ks < 4; ++ks) bfr[ks] = *(const s16x8*)(wp + ks * 32);
#pragma unroll
      for (int mt = 0; mt < 4; ++mt) {
        f32x4 acc = {0.f, 0.f, 0.f, 0.f};
#pragma unroll
        for (int ks = 0; ks < 4; ++ks) {
          s16x8 a = *(const s16x8*)(xs_s + (mt * 16 + ln15) * 136 + ks * 32 + quad * 8);
          acc = mfma16(a, bfr[ks], acc);
        }
        int tok0 = mt * 16 + m_sub;
        if (n0 < 128) {               // q
#pragma unroll
          for (int r = 0; r < 4; ++r) q_s[(tok0 + r) * 136 + n] = f2bf(acc[r]);
        } else if (n0 < 256) {        // k
          int nn = n - 128;
#pragma unroll
          for (int r = 0; r < 4; ++r) k_s[(tok0 + r) * 136 + nn] = f2bf(acc[r]);
        } else {                      // v (transposed [ch][tok])
          int nn = n - 256;
          ushort4 pk;
          pk.x = f2bf(acc[0]); pk.y = f2bf(acc[1]);
          pk.z = f2bf(acc[2]); pk.w = f2bf(acc[3]);
          *(ushort4*)(v_s + nn * 72 + tok0) = pk;
        }
      }
    }
  }
  __syncthreads();

  // ---- phase 2: QK^T * scale + bias -> S; task = (head, m-tile) per wave --
  {
    const int h  = wave >> 2;
    const int mt = wave & 3;
    unsigned short* Sh = S_s + h * 64 * 72;
    s16x8 qf = *(const s16x8*)(q_s + (mt * 16 + ln15) * 136 + h * 32 + quad * 8);
    const float scale = 0.17677669529663687f;   // 32^-0.5
#pragma unroll
    for (int nt = 0; nt < 4; ++nt) {
      s16x8 kf = *(const s16x8*)(k_s + (nt * 16 + ln15) * 136 + h * 32 + quad * 8);
      f32x4 acc = {0.f, 0.f, 0.f, 0.f};
      acc = mfma16(qf, kf, acc);
      int nn = nt * 16 + ln15;
      int tok0 = mt * 16 + m_sub;
#pragma unroll
      for (int r = 0; r < 4; ++r) {
        float sv = acc[r] * scale + bias_s[(tok0 + r) * 65 + nn];
        Sh[(tok0 + r) * 72 + nn] = f2bf(sv);
      }
    }
  }
  __syncthreads();

  // ---- phase 3: softmax; 4 lanes per row (quad = 16-col slice) ------------
  {
    const int h   = wave >> 2;
    const int row = (wave & 3) * 16 + ln15;
    unsigned short* rp = S_s + h * 64 * 72 + row * 72 + quad * 16;
    float vals[16];
    float mx = -1e30f;
#pragma unroll
    for (int c = 0; c < 2; ++c) {
      s16x8 s8 = *(const s16x8*)(rp + c * 8);
#pragma unroll
      for (int j = 0; j < 8; ++j) {
        float f = bf2f((unsigned short)s8[j]);
        vals[c * 8 + j] = f;
        mx = fmaxf(mx, f);
      }
    }
    mx = fmaxf(mx, __shfl_xor(mx, 16));
    mx = fmaxf(mx, __shfl_xor(mx, 32));
    float sum = 0.f;
#pragma unroll
    for (int c = 0; c < 2; ++c) {
      s16x8 st;
#pragma unroll
      for (int j = 0; j < 8; ++j) {
        float e = __expf(vals[c * 8 + j] - mx);
        sum += e;
        st[j] = (short)f2bf(e);
      }
      *(s16x8*)(rp + c * 8) = st;
    }
    sum += __shfl_xor(sum, 16);
    sum += __shfl_xor(sum, 32);
    if (quad == 0) rsum_s[h * 64 + row] = 1.0f / sum;
  }
  __syncthreads();

  // ---- phase 4: PV (M=64,K=64,N=32); task = (head, m-tile) per wave -------
  {
    const int h  = wave >> 2;
    const int mt = wave & 3;
    unsigned short* Sh = S_s + h * 64 * 72;
    s16x8 pf[2];
#pragma unroll
    for (int ks = 0; ks < 2; ++ks)
      pf[ks] = *(const s16x8*)(Sh + (mt * 16 + ln15) * 72 + ks * 32 + quad * 8);
    int tok0 = mt * 16 + m_sub;
    float rc[4];
#pragma unroll
    for (int r = 0; r < 4; ++r) rc[r] = rsum_s[h * 64 + tok0 + r];
#pragma unroll
    for (int nt = 0; nt < 2; ++nt) {
      f32x4 acc = {0.f, 0.f, 0.f, 0.f};
#pragma unroll
      for (int ks = 0; ks < 2; ++ks) {
        s16x8 vf = *(const s16x8*)(v_s + (h * 32 + nt * 16 + ln15) * 72 + ks * 32 + quad * 8);
        acc = mfma16(pf[ks], vf, acc);
      }
      int n = h * 32 + nt * 16 + ln15;
#pragma unroll
      for (int r = 0; r < 4; ++r)
        oa_s[(tok0 + r) * 136 + n] = f2bf(acc[r] * rc[r]);
    }
  }
  __syncthreads();

  // ---- phase 5: out proj (M=64,K=128,N=128); task = (n-tile, mt-pair) -----
  {
    const int nt  = wave >> 1;           // 0..7
    const int mtb = (wave & 1) * 2;      // {0,2}
    int n = nt * 16 + ln15;
    s16x8 bfr[4];
    const unsigned short* wp = woutT + n * 128 + quad * 8;
#pragma unroll
    for (int ks = 0; ks < 4; ++ks) bfr[ks] = *(const s16x8*)(wp + ks * 32);
    float bo = b_out[n];
#pragma unroll
    for (int mi = 0; mi < 2; ++mi) {
      int mt = mtb + mi;
      f32x4 acc = {0.f, 0.f, 0.f, 0.f};
#pragma unroll
      for (int ks = 0; ks < 4; ++ks) {
        s16x8 a = *(const s16x8*)(oa_s + (mt * 16 + ln15) * 136 + ks * 32 + quad * 8);
        acc = mfma16(a, bfr[ks], acc);
      }
      int tok0 = mt * 16 + m_sub;
#pragma unroll
      for (int r = 0; r < 4; ++r) {
        int tok = tok0 + r;
        int ti = tok >> 3, tj = tok & 7;
        int gi = (wh * 8 + ti + 4) & 127;
        int gj = (ww * 8 + tj + 4) & 127;
        out[((b * 128 + gi) * 128 + gj) * 128 + n] = acc[r] + bo;
      }
    }
  }
}

extern "C" void kernel_launch(void* const* d_in, const int* in_sizes, int n_in,
                              void* d_out, int out_size, void* d_ws, size_t ws_size,
                              hipStream_t stream) {
  const float* x    = (const float*)d_in[0];
  const float* wqkv = (const float*)d_in[1];
  const float* wout = (const float*)d_in[2];
  const float* bout = (const float*)d_in[3];
  const float* pe   = (const float*)d_in[4];
  const float* ulm  = (const float*)d_in[5];
  const float* lrm  = (const float*)d_in[6];

  unsigned short* wqkvT = (unsigned short*)d_ws;           // 384*128 bf16
  unsigned short* woutT = wqkvT + 384 * 128;               // 128*128 bf16

  prep_weights<<<(384 * 128 + 128 * 128) / 256, 256, 0, stream>>>(wqkv, wout, wqkvT, woutT);
  swin_fused<<<16 * 256, 1024, 0, stream>>>(x, wqkvT, woutT, bout, pe, ulm, lrm,
                                            (float*)d_out);
}